// Round 3
// baseline (661.326 us; speedup 1.0000x reference)
//
#include <hip/hip_runtime.h>
#include <cstdint>
#include <cstddef>

#define HH 96
#define WW 96
#define NN 8
#define CIN 512
#define CMID 256
#define CO2 576

typedef __attribute__((ext_vector_type(4))) float f32x4;
typedef __attribute__((ext_vector_type(8))) short short8;

static __device__ __forceinline__ unsigned short f2bf(float f) {
    unsigned int u = __float_as_uint(f);
    u += 0x7fffu + ((u >> 16) & 1u);
    return (unsigned short)(u >> 16);
}

// w1 (256,512,3,3) OIHW fp32 -> w1t [9][256][512] bf16 ; w2 (576,256) -> bf16
__global__ __launch_bounds__(256) void prep_w_kernel(
    const float* __restrict__ w1, const float* __restrict__ w2,
    unsigned short* __restrict__ w1t, unsigned short* __restrict__ w2t)
{
    size_t i = (size_t)blockIdx.x * 256 + threadIdx.x;
    if (i < (size_t)9 * CMID * CIN) {
        int tap = (int)(i / (CMID * CIN));
        int r   = (int)(i % (CMID * CIN));
        int co = r / CIN, ci = r % CIN;
        w1t[i] = f2bf(w1[((size_t)co * CIN + ci) * 9 + tap]);
    }
    if (i < (size_t)CO2 * CMID) {
        w2t[i] = f2bf(w2[i]);
    }
}

// feature (N,512,96,96) fp32 -> featT [N][H][W][512] bf16
__global__ __launch_bounds__(256) void transpose_kernel(
    const float* __restrict__ f, unsigned short* __restrict__ ft)
{
    __shared__ float t[96 * 65];
    const int tid = threadIdx.x;
    const int b = blockIdx.x;
    const int n = b / HH, h = b % HH;
    for (int cb = 0; cb < 8; ++cb) {
        __syncthreads();
        #pragma unroll
        for (int it = 0; it < 24; ++it) {
            int idx = tid + it * 256;          // 0..6143
            int cl = idx / 96, w = idx - cl * 96;
            t[w * 65 + cl] = f[(((size_t)n * CIN + cb * 64 + cl) * HH + h) * WW + w];
        }
        __syncthreads();
        #pragma unroll
        for (int it = 0; it < 24; ++it) {
            int idx = tid + it * 256;
            int w = idx >> 6, cl = idx & 63;
            ft[(((size_t)n * HH + h) * WW + w) * CIN + cb * 64 + cl] = f2bf(t[w * 65 + cl]);
        }
    }
}

// conv1: 3x3, 512->256, bias+ReLU. One block per (n,h).
// 2-phase reg-staged double-buffered pipeline, 32-ci K-chunks.
// LDS chunk layout [lw][r'][slot'][8 bf16] with dual XOR swizzle:
//   r' = r ^ ((lw>>2)&3)  (pad row r=3 absorbs image), slot' = slot ^ (lw&3)
// -> bank-uniform for wave64 ds_read_b128 / ds_write_b128 (8/bank minimum).
__global__ __launch_bounds__(256, 2) void conv1_kernel(
    const unsigned short* __restrict__ featT,
    const unsigned short* __restrict__ w1t,
    const float* __restrict__ b1,
    unsigned short* __restrict__ x)
{
    __shared__ unsigned short fs[2 * 98 * 128];   // 2 x 25088 B = 50176 B
    const int tid = threadIdx.x;
    int bid = blockIdx.x;
    bid = (bid & 7) * 96 + (bid >> 3);            // XCD-aware swizzle (768 = 8*96)
    const int n = bid / HH, h = bid % HH;
    const int wave = tid >> 6, lane = tid & 63;
    const int g = lane >> 4, sl = lane & 15;

    f32x4 acc[6][4];
    #pragma unroll
    for (int i = 0; i < 6; ++i)
        #pragma unroll
        for (int j = 0; j < 4; ++j) acc[i][j] = (f32x4)0.0f;

    // per-thread staging slots: 1152 16B-chunks per 32-ci iter, 4.5 per thread
    bool act[5], vld[5];
    int gidx[5];      // featT element index (ci chunk offset added per iter)
    int ldsoff[5];    // fs short-index within a buffer (swizzled)
    #pragma unroll
    for (int k = 0; k < 5; ++k) {
        int l = tid + k * 256;
        act[k] = (l < 1152);
        int ll = act[k] ? l : 0;
        int seg = ll / 96, w = ll - seg * 96;
        int r = seg >> 2, s = seg & 3;
        int hh2 = h + r - 1;
        vld[k] = act[k] && ((unsigned)hh2 < HH);
        int hsafe = ((unsigned)hh2 < HH) ? hh2 : 0;
        gidx[k] = ((n * HH + hsafe) * WW + w) * CIN + s * 8;
        int lw = w + 1;
        ldsoff[k] = lw * 128 + ((r ^ ((lw >> 2) & 3)) << 5) + ((s ^ (lw & 3)) << 3);
    }

    short8 stg[5];
    // prologue: prefetch chunk 0
    #pragma unroll
    for (int k = 0; k < 5; ++k) {
        short8 v = (short8)0;
        if (vld[k]) v = *reinterpret_cast<const short8*>(&featT[gidx[k]]);
        stg[k] = v;
    }
    // zero the halo pad columns (lw=0, lw=97) of both buffers, once
    if (tid < 48) {
        int bb = tid / 24, rem = tid - bb * 24;
        int c2 = rem / 12, rs = rem - c2 * 12;
        int r = rs >> 2, s = rs & 3;
        int lw = c2 ? 97 : 0;
        int off = bb * (98 * 128) + lw * 128 +
                  ((r ^ ((lw >> 2) & 3)) << 5) + ((s ^ (lw & 3)) << 3);
        *reinterpret_cast<short8*>(&fs[off]) = (short8)0;
    }
    #pragma unroll
    for (int k = 0; k < 5; ++k)
        if (act[k]) *reinterpret_cast<short8*>(&fs[ldsoff[k]]) = stg[k];
    __syncthreads();

    for (int it = 0; it < 16; ++it) {
        const int buf = it & 1;
        const int bufbase = buf * (98 * 128);
        // issue next-chunk global loads early (latency hides under MFMA)
        if (it < 15) {
            #pragma unroll
            for (int k = 0; k < 5; ++k) {
                short8 v = (short8)0;
                if (vld[k]) v = *reinterpret_cast<const short8*>(
                    &featT[gidx[k] + (it + 1) * 32]);
                stg[k] = v;
            }
        }
        // compute on current buffer
        #pragma unroll
        for (int ki = 0; ki < 3; ++ki) {
            #pragma unroll
            for (int kj = 0; kj < 3; ++kj) {
                const int tap = ki * 3 + kj;
                short8 af[4];
                const unsigned short* ab = &w1t[(size_t)tap * CMID * CIN + it * 32 + g * 8];
                #pragma unroll
                for (int tc = 0; tc < 4; ++tc)
                    af[tc] = *reinterpret_cast<const short8*>(
                        &ab[(size_t)(wave * 64 + tc * 16 + sl) * CIN]);
                #pragma unroll
                for (int ts = 0; ts < 6; ++ts) {
                    int lw = ts * 16 + sl + kj;
                    int off = bufbase + lw * 128 +
                              ((ki ^ ((lw >> 2) & 3)) << 5) + ((g ^ (lw & 3)) << 3);
                    short8 bf = *reinterpret_cast<const short8*>(&fs[off]);
                    #pragma unroll
                    for (int tc = 0; tc < 4; ++tc)
                        acc[ts][tc] = __builtin_amdgcn_mfma_f32_16x16x32_bf16(
                            af[tc], bf, acc[ts][tc], 0, 0, 0);
                }
            }
        }
        // write prefetched chunk into the other buffer, single barrier per iter
        if (it < 15) {
            const int obase = (buf ^ 1) * (98 * 128);
            #pragma unroll
            for (int k = 0; k < 5; ++k)
                if (act[k]) *reinterpret_cast<short8*>(&fs[obase + ldsoff[k]]) = stg[k];
            __syncthreads();
        }
    }

    // epilogue: bias + ReLU -> bf16 x[n][h][w][co]
    const size_t rowbase = ((size_t)n * HH + h);
    #pragma unroll
    for (int ts = 0; ts < 6; ++ts) {
        int s = ts * 16 + sl;
        unsigned short* xp = &x[(rowbase * WW + s) * CMID];
        #pragma unroll
        for (int tc = 0; tc < 4; ++tc) {
            int co0 = wave * 64 + tc * 16 + g * 4;
            const float4 bb = *reinterpret_cast<const float4*>(&b1[co0]);
            float v0 = acc[ts][tc][0] + bb.x;
            float v1 = acc[ts][tc][1] + bb.y;
            float v2 = acc[ts][tc][2] + bb.z;
            float v3 = acc[ts][tc][3] + bb.w;
            v0 = v0 > 0.f ? v0 : 0.f;
            v1 = v1 > 0.f ? v1 : 0.f;
            v2 = v2 > 0.f ? v2 : 0.f;
            v3 = v3 > 0.f ? v3 : 0.f;
            ushort4 st;
            st.x = f2bf(v0); st.y = f2bf(v1); st.z = f2bf(v2); st.w = f2bf(v3);
            *reinterpret_cast<ushort4*>(&xp[co0]) = st;
        }
    }
}

// conv2 (1x1, 256->576) + bias*0.25 + softmax over 9 taps + flow assembly
__global__ __launch_bounds__(384) void conv2_kernel(
    const unsigned short* __restrict__ x,
    const unsigned short* __restrict__ w2t,
    const float* __restrict__ b2,
    const float* __restrict__ flow,
    float* __restrict__ out)
{
    __shared__ float lo[16 * 768];
    const int tid = threadIdx.x;
    const int b = blockIdx.x;
    const int n = b / HH, h = b % HH;
    const int wave = tid >> 6, lane = tid & 63;
    const int g = lane >> 4, sl = lane & 15;
    const int s = wave * 16 + sl;

    f32x4 acc[36];
    #pragma unroll
    for (int i = 0; i < 36; ++i) acc[i] = (f32x4)0.0f;

    const unsigned short* xrow = &x[(((size_t)n * HH + h) * WW) * CMID];
    #pragma unroll
    for (int kc = 0; kc < 8; ++kc) {
        short8 bf = *reinterpret_cast<const short8*>(&xrow[s * CMID + kc * 32 + g * 8]);
        #pragma unroll
        for (int tc = 0; tc < 36; ++tc) {
            short8 af = *reinterpret_cast<const short8*>(
                &w2t[(size_t)(tc * 16 + sl) * CMID + kc * 32 + g * 8]);
            acc[tc] = __builtin_amdgcn_mfma_f32_16x16x32_bf16(af, bf, acc[tc], 0, 0, 0);
        }
    }

    #pragma unroll
    for (int tc = 0; tc < 36; ++tc) {
        const float4 bb = *reinterpret_cast<const float4*>(&b2[tc * 16 + g * 4]);
        acc[tc][0] = 0.25f * (acc[tc][0] + bb.x);
        acc[tc][1] = 0.25f * (acc[tc][1] + bb.y);
        acc[tc][2] = 0.25f * (acc[tc][2] + bb.z);
        acc[tc][3] = 0.25f * (acc[tc][3] + bb.w);
    }

    float pf[2][9];
    #pragma unroll
    for (int ch = 0; ch < 2; ++ch) {
        #pragma unroll
        for (int ki = 0; ki < 3; ++ki) {
            #pragma unroll
            for (int kj = 0; kj < 3; ++kj) {
                int hh2 = h + ki - 1, ww2 = s + kj - 1;
                float v = 0.f;
                if ((unsigned)hh2 < HH && (unsigned)ww2 < WW)
                    v = flow[(((size_t)n * 2 + ch) * HH + hh2) * WW + ww2];
                pf[ch][ki * 3 + kj] = 8.f * v;
            }
        }
    }

    #pragma unroll
    for (int mp = 0; mp < 4; ++mp) {
        #pragma unroll
        for (int i = 0; i < 4; ++i) {
            int pp = mp * 16 + g * 4 + i;
            float L[9];
            #pragma unroll
            for (int k = 0; k < 9; ++k) L[k] = acc[mp + 4 * k][i];
            float mx = L[0];
            #pragma unroll
            for (int k = 1; k < 9; ++k) mx = fmaxf(mx, L[k]);
            float e[9], sum = 0.f;
            #pragma unroll
            for (int k = 0; k < 9; ++k) { e[k] = __expf(L[k] - mx); sum += e[k]; }
            float inv = 1.f / sum;
            int py = pp >> 3, px = pp & 7;
            #pragma unroll
            for (int ch = 0; ch < 2; ++ch) {
                float o = 0.f;
                #pragma unroll
                for (int k = 0; k < 9; ++k) o += e[k] * pf[ch][k];
                lo[(ch * 8 + py) * 768 + s * 8 + px] = o * inv;
            }
        }
    }
    __syncthreads();

    #pragma unroll
    for (int it = 0; it < 8; ++it) {
        int idx = tid + it * 384;
        int row = idx / 192, c4 = idx - row * 192;
        int ch = row >> 3, py = row & 7;
        float4 v = *reinterpret_cast<const float4*>(&lo[row * 768 + c4 * 4]);
        *reinterpret_cast<float4*>(
            &out[(((size_t)n * 2 + ch) * 768 + h * 8 + py) * 768 + c4 * 4]) = v;
    }
}

extern "C" void kernel_launch(void* const* d_in, const int* in_sizes, int n_in,
                              void* d_out, int out_size, void* d_ws, size_t ws_size,
                              hipStream_t stream)
{
    const float* feature = (const float*)d_in[0];
    const float* flow    = (const float*)d_in[1];
    const float* w1      = (const float*)d_in[2];
    const float* b1      = (const float*)d_in[3];
    const float* w2      = (const float*)d_in[4];
    const float* b2      = (const float*)d_in[5];
    float* out = (float*)d_out;

    const size_t featT_bytes = (size_t)NN * HH * WW * CIN * 2;
    const size_t x_bytes     = (size_t)NN * HH * WW * CMID * 2;
    const size_t w1t_bytes   = (size_t)9 * CMID * CIN * 2;
    const size_t w2t_bytes   = (size_t)CO2 * CMID * 2;
    if (ws_size < featT_bytes + x_bytes + w1t_bytes + w2t_bytes) return;

    char* ws = (char*)d_ws;
    unsigned short* featT = (unsigned short*)ws;
    unsigned short* xbuf  = (unsigned short*)(ws + featT_bytes);
    unsigned short* w1t   = (unsigned short*)(ws + featT_bytes + x_bytes);
    unsigned short* w2t   = (unsigned short*)(ws + featT_bytes + x_bytes + w1t_bytes);

    prep_w_kernel<<<4608, 256, 0, stream>>>(w1, w2, w1t, w2t);
    transpose_kernel<<<NN * HH, 256, 0, stream>>>(feature, featT);
    conv1_kernel<<<NN * HH, 256, 0, stream>>>(featT, w1t, b1, xbuf);
    conv2_kernel<<<NN * HH, 384, 0, stream>>>(xbuf, w2t, b2, flow, out);
}

// Round 4
// 593.836 us; speedup vs baseline: 1.1136x; 1.1136x over previous
//
#include <hip/hip_runtime.h>
#include <cstdint>
#include <cstddef>

#define HH 96
#define WW 96
#define NN 8
#define CIN 512
#define CMID 256
#define CO2 576

typedef __attribute__((ext_vector_type(4))) float f32x4;
typedef __attribute__((ext_vector_type(8))) short short8;

static __device__ __forceinline__ unsigned short f2bf(float f) {
    unsigned int u = __float_as_uint(f);
    u += 0x7fffu + ((u >> 16) & 1u);
    return (unsigned short)(u >> 16);
}

// w1 (256,512,3,3) OIHW fp32 -> w1p: 144 slabs [(cc,tap)] of 8192 shorts:
//   i = slab*8192 + co16*512 + g*128 + sl*8 + e
//   co = co16*16+sl, ci = cc*32 + g*8 + e   (fragment order: wave reads 64
//   consecutive 16B chunks per af-load)
// w2 (576,256) -> bf16
__global__ __launch_bounds__(256) void prep_w_kernel(
    const float* __restrict__ w1, const float* __restrict__ w2,
    unsigned short* __restrict__ w1p, unsigned short* __restrict__ w2t)
{
    size_t i = (size_t)blockIdx.x * 256 + threadIdx.x;
    if (i < (size_t)144 * 8192) {
        int sb = (int)(i >> 13);
        int r13 = (int)(i & 8191);
        int co16 = r13 >> 9;
        int g = (r13 >> 7) & 3;
        int sl = (r13 >> 3) & 15;
        int e = (int)(i & 7);
        int cc = sb / 9, tap = sb % 9;
        int co = co16 * 16 + sl;
        int ci = cc * 32 + g * 8 + e;
        w1p[i] = f2bf(w1[((size_t)co * CIN + ci) * 9 + tap]);
    }
    if (i < (size_t)CO2 * CMID) {
        w2t[i] = f2bf(w2[i]);
    }
}

// feature (N,512,96,96) fp32 -> featT [N][H][W][512] bf16
__global__ __launch_bounds__(256) void transpose_kernel(
    const float* __restrict__ f, unsigned short* __restrict__ ft)
{
    __shared__ float t[96 * 65];
    const int tid = threadIdx.x;
    const int b = blockIdx.x;
    const int n = b / HH, h = b % HH;
    for (int cb = 0; cb < 8; ++cb) {
        __syncthreads();
        #pragma unroll
        for (int it = 0; it < 24; ++it) {
            int idx = tid + it * 256;
            int cl = idx / 96, w = idx - cl * 96;
            t[w * 65 + cl] = f[(((size_t)n * CIN + cb * 64 + cl) * HH + h) * WW + w];
        }
        __syncthreads();
        #pragma unroll
        for (int it = 0; it < 24; ++it) {
            int idx = tid + it * 256;
            int w = idx >> 6, cl = idx & 63;
            ft[(((size_t)n * HH + h) * WW + w) * CIN + cb * 64 + cl] = f2bf(t[w * 65 + cl]);
        }
    }
}

// conv1 v4: 3x3, 512->256, bias+ReLU.
// Block = 2 output rows, 512 threads = 8 waves (2 rows x 4 co-groups).
// A (weights) staged through LDS from pre-permuted w1p, double-buffered per
// (32-ci chunk, tap); B (4 halo rows) single-buffered per chunk, reg-staged
// issue-early/write-late. Grid 384 = 8n x 48 rowpairs.
__global__ __launch_bounds__(512, 2) void conv1_kernel(
    const unsigned short* __restrict__ featT,
    const unsigned short* __restrict__ w1p,
    const float* __restrict__ b1,
    unsigned short* __restrict__ x)
{
    __shared__ unsigned short fsB[4 * 98 * 32];   // 25088 B  [r][lw][slot^][8]
    __shared__ unsigned short fsA[2][8192];       // 32768 B  2 x 16KB slabs
    const int tid = threadIdx.x;
    int bid = blockIdx.x;
    bid = (bid & 7) * 48 + (bid >> 3);            // XCD swizzle (384 = 8*48)
    const int n = bid / 48, rp = bid % 48;
    const int h0 = rp * 2;
    const int wave = tid >> 6, lane = tid & 63;
    const int wc = wave & 3, wr = wave >> 2;      // co-group, row
    const int g = lane >> 4, sl = lane & 15;

    f32x4 acc[6][4];
    #pragma unroll
    for (int i = 0; i < 6; ++i)
        #pragma unroll
        for (int j = 0; j < 4; ++j) acc[i][j] = (f32x4)0.0f;

    // B staging maps: 1536 chunks = [w(96)][r(4)][s(4)], 3 per thread
    int gB[3], lB[3];
    bool vB[3];
    #pragma unroll
    for (int k = 0; k < 3; ++k) {
        int idx = k * 512 + tid;
        int w = idx >> 4, r = (idx >> 2) & 3, s = idx & 3;
        int row = h0 - 1 + r;
        vB[k] = (unsigned)row < HH;
        int rs = vB[k] ? row : 0;
        gB[k] = ((n * HH + rs) * WW + w) * CIN + s * 8;   // + cc*32 per chunk
        int lw = w + 1;
        lB[k] = ((r * 98 + lw) * 4 + (s ^ (lw & 3))) * 8;
    }

    short8 bstg[3], astg[2];

    // prologue: zero halo pad columns (lw=0,97), load A slab 0 + B chunk 0
    if (tid < 32) {
        int r = tid >> 3, col = (tid >> 2) & 1, s = tid & 3;
        int lw = col ? 97 : 0;
        *reinterpret_cast<short8*>(
            &fsB[((r * 98 + lw) * 4 + (s ^ (lw & 3))) * 8]) = (short8)0;
    }
    astg[0] = *reinterpret_cast<const short8*>(&w1p[(size_t)tid * 8]);
    astg[1] = *reinterpret_cast<const short8*>(&w1p[(size_t)(tid + 512) * 8]);
    #pragma unroll
    for (int k = 0; k < 3; ++k) {
        short8 v = (short8)0;
        if (vB[k]) v = *reinterpret_cast<const short8*>(&featT[gB[k]]);
        bstg[k] = v;
    }
    *reinterpret_cast<short8*>(&fsA[0][tid * 8]) = astg[0];
    *reinterpret_cast<short8*>(&fsA[0][(tid + 512) * 8]) = astg[1];
    #pragma unroll
    for (int k = 0; k < 3; ++k)
        *reinterpret_cast<short8*>(&fsB[lB[k]]) = bstg[k];
    __syncthreads();

    for (int cc = 0; cc < 16; ++cc) {
        if (cc > 0) {
            // write prefetched B chunk (loads issued at tap 7 of cc-1)
            #pragma unroll
            for (int k = 0; k < 3; ++k)
                *reinterpret_cast<short8*>(&fsB[lB[k]]) = bstg[k];
            __syncthreads();
        }
        #pragma unroll
        for (int tap = 0; tap < 9; ++tap) {
            const int sb = cc * 9 + tap;
            // prefetch next A slab (16KB, perfectly coalesced)
            if (sb < 143) {
                const unsigned short* ap = &w1p[(size_t)(sb + 1) * 8192];
                astg[0] = *reinterpret_cast<const short8*>(&ap[tid * 8]);
                astg[1] = *reinterpret_cast<const short8*>(&ap[(tid + 512) * 8]);
            }
            // prefetch next B chunk late in the tap sequence
            if (tap == 7 && cc < 15) {
                #pragma unroll
                for (int k = 0; k < 3; ++k) {
                    short8 v = (short8)0;
                    if (vB[k]) v = *reinterpret_cast<const short8*>(
                        &featT[gB[k] + (cc + 1) * 32]);
                    bstg[k] = v;
                }
            }
            // compute: af = 64 consecutive 16B chunks per (wc,tc); bf swizzled
            const int ab = sb & 1;
            const int ki = tap / 3, kj = tap % 3;
            short8 af[4];
            #pragma unroll
            for (int tc = 0; tc < 4; ++tc)
                af[tc] = *reinterpret_cast<const short8*>(
                    &fsA[ab][((wc * 4 + tc) * 64 + lane) * 8]);
            #pragma unroll
            for (int ts = 0; ts < 6; ++ts) {
                int lw = ts * 16 + sl + kj;
                short8 bf = *reinterpret_cast<const short8*>(
                    &fsB[(((wr + ki) * 98 + lw) * 4 + (g ^ (lw & 3))) * 8]);
                #pragma unroll
                for (int tc = 0; tc < 4; ++tc)
                    acc[ts][tc] = __builtin_amdgcn_mfma_f32_16x16x32_bf16(
                        af[tc], bf, acc[ts][tc], 0, 0, 0);
            }
            // write next A slab into the other buffer
            if (sb < 143) {
                *reinterpret_cast<short8*>(&fsA[ab ^ 1][tid * 8]) = astg[0];
                *reinterpret_cast<short8*>(&fsA[ab ^ 1][(tid + 512) * 8]) = astg[1];
            }
            __syncthreads();
        }
    }

    // epilogue: bias + ReLU -> bf16 x[n][h0+wr][sp][co]
    const size_t rowbase = ((size_t)n * HH + h0 + wr);
    #pragma unroll
    for (int ts = 0; ts < 6; ++ts) {
        int sp = ts * 16 + sl;
        unsigned short* xp = &x[(rowbase * WW + sp) * CMID];
        #pragma unroll
        for (int tc = 0; tc < 4; ++tc) {
            int co0 = wc * 64 + tc * 16 + g * 4;
            const float4 bb = *reinterpret_cast<const float4*>(&b1[co0]);
            float v0 = acc[ts][tc][0] + bb.x;
            float v1 = acc[ts][tc][1] + bb.y;
            float v2 = acc[ts][tc][2] + bb.z;
            float v3 = acc[ts][tc][3] + bb.w;
            v0 = v0 > 0.f ? v0 : 0.f;
            v1 = v1 > 0.f ? v1 : 0.f;
            v2 = v2 > 0.f ? v2 : 0.f;
            v3 = v3 > 0.f ? v3 : 0.f;
            ushort4 st;
            st.x = f2bf(v0); st.y = f2bf(v1); st.z = f2bf(v2); st.w = f2bf(v3);
            *reinterpret_cast<ushort4*>(&xp[co0]) = st;
        }
    }
}

// conv2 (1x1, 256->576) + bias*0.25 + softmax over 9 taps + flow assembly
__global__ __launch_bounds__(384) void conv2_kernel(
    const unsigned short* __restrict__ x,
    const unsigned short* __restrict__ w2t,
    const float* __restrict__ b2,
    const float* __restrict__ flow,
    float* __restrict__ out)
{
    __shared__ float lo[16 * 768];
    const int tid = threadIdx.x;
    const int b = blockIdx.x;
    const int n = b / HH, h = b % HH;
    const int wave = tid >> 6, lane = tid & 63;
    const int g = lane >> 4, sl = lane & 15;
    const int s = wave * 16 + sl;

    f32x4 acc[36];
    #pragma unroll
    for (int i = 0; i < 36; ++i) acc[i] = (f32x4)0.0f;

    const unsigned short* xrow = &x[(((size_t)n * HH + h) * WW) * CMID];
    #pragma unroll
    for (int kc = 0; kc < 8; ++kc) {
        short8 bf = *reinterpret_cast<const short8*>(&xrow[s * CMID + kc * 32 + g * 8]);
        #pragma unroll
        for (int tc = 0; tc < 36; ++tc) {
            short8 af = *reinterpret_cast<const short8*>(
                &w2t[(size_t)(tc * 16 + sl) * CMID + kc * 32 + g * 8]);
            acc[tc] = __builtin_amdgcn_mfma_f32_16x16x32_bf16(af, bf, acc[tc], 0, 0, 0);
        }
    }

    #pragma unroll
    for (int tc = 0; tc < 36; ++tc) {
        const float4 bb = *reinterpret_cast<const float4*>(&b2[tc * 16 + g * 4]);
        acc[tc][0] = 0.25f * (acc[tc][0] + bb.x);
        acc[tc][1] = 0.25f * (acc[tc][1] + bb.y);
        acc[tc][2] = 0.25f * (acc[tc][2] + bb.z);
        acc[tc][3] = 0.25f * (acc[tc][3] + bb.w);
    }

    float pf[2][9];
    #pragma unroll
    for (int ch = 0; ch < 2; ++ch) {
        #pragma unroll
        for (int ki = 0; ki < 3; ++ki) {
            #pragma unroll
            for (int kj = 0; kj < 3; ++kj) {
                int hh2 = h + ki - 1, ww2 = s + kj - 1;
                float v = 0.f;
                if ((unsigned)hh2 < HH && (unsigned)ww2 < WW)
                    v = flow[(((size_t)n * 2 + ch) * HH + hh2) * WW + ww2];
                pf[ch][ki * 3 + kj] = 8.f * v;
            }
        }
    }

    #pragma unroll
    for (int mp = 0; mp < 4; ++mp) {
        #pragma unroll
        for (int i = 0; i < 4; ++i) {
            int pp = mp * 16 + g * 4 + i;
            float L[9];
            #pragma unroll
            for (int k = 0; k < 9; ++k) L[k] = acc[mp + 4 * k][i];
            float mx = L[0];
            #pragma unroll
            for (int k = 1; k < 9; ++k) mx = fmaxf(mx, L[k]);
            float e[9], sum = 0.f;
            #pragma unroll
            for (int k = 0; k < 9; ++k) { e[k] = __expf(L[k] - mx); sum += e[k]; }
            float inv = 1.f / sum;
            int py = pp >> 3, px = pp & 7;
            #pragma unroll
            for (int ch = 0; ch < 2; ++ch) {
                float o = 0.f;
                #pragma unroll
                for (int k = 0; k < 9; ++k) o += e[k] * pf[ch][k];
                lo[(ch * 8 + py) * 768 + s * 8 + px] = o * inv;
            }
        }
    }
    __syncthreads();

    #pragma unroll
    for (int it = 0; it < 8; ++it) {
        int idx = tid + it * 384;
        int row = idx / 192, c4 = idx - row * 192;
        int ch = row >> 3, py = row & 7;
        float4 v = *reinterpret_cast<const float4*>(&lo[row * 768 + c4 * 4]);
        *reinterpret_cast<float4*>(
            &out[(((size_t)n * 2 + ch) * 768 + h * 8 + py) * 768 + c4 * 4]) = v;
    }
}

extern "C" void kernel_launch(void* const* d_in, const int* in_sizes, int n_in,
                              void* d_out, int out_size, void* d_ws, size_t ws_size,
                              hipStream_t stream)
{
    const float* feature = (const float*)d_in[0];
    const float* flow    = (const float*)d_in[1];
    const float* w1      = (const float*)d_in[2];
    const float* b1      = (const float*)d_in[3];
    const float* w2      = (const float*)d_in[4];
    const float* b2      = (const float*)d_in[5];
    float* out = (float*)d_out;

    const size_t featT_bytes = (size_t)NN * HH * WW * CIN * 2;
    const size_t x_bytes     = (size_t)NN * HH * WW * CMID * 2;
    const size_t w1p_bytes   = (size_t)144 * 8192 * 2;           // same as before
    const size_t w2t_bytes   = (size_t)CO2 * CMID * 2;
    if (ws_size < featT_bytes + x_bytes + w1p_bytes + w2t_bytes) return;

    char* ws = (char*)d_ws;
    unsigned short* featT = (unsigned short*)ws;
    unsigned short* xbuf  = (unsigned short*)(ws + featT_bytes);
    unsigned short* w1p   = (unsigned short*)(ws + featT_bytes + x_bytes);
    unsigned short* w2t   = (unsigned short*)(ws + featT_bytes + x_bytes + w1p_bytes);

    prep_w_kernel<<<4608, 256, 0, stream>>>(w1, w2, w1p, w2t);
    transpose_kernel<<<NN * HH, 256, 0, stream>>>(feature, featT);
    conv1_kernel<<<384, 512, 0, stream>>>(featT, w1p, b1, xbuf);
    conv2_kernel<<<NN * HH, 384, 0, stream>>>(xbuf, w2t, b2, flow, out);
}